// Round 13
// baseline (93.755 us; speedup 1.0000x reference)
//
#include <hip/hip_runtime.h>

namespace {
constexpr int Bx = 8, Cc = 64, Hh = 128, Ww = 128, Co = 64;
constexpr int Ll = Hh * Ww;        // 16384 = 2^14
constexpr int NPIX = Bx * Ll;      // 131072
constexpr int TP = 64;             // pixels per block in k23
}

using short8 = __attribute__((ext_vector_type(8))) short;
using f32x4  = __attribute__((ext_vector_type(4))) float;

__device__ __forceinline__ unsigned short f32_to_bf16(float f) {
    union { float f; unsigned u; } un; un.f = f;
    unsigned r = un.u + 0x7FFFu + ((un.u >> 16) & 1u);   // round-to-nearest-even
    return (unsigned short)(r >> 16);
}
// packed pair via HW converter (RNE); no builtin on gfx950 -> inline asm
__device__ __forceinline__ unsigned cvt_pk_bf16(float lo, float hi) {
    unsigned u;
    asm("v_cvt_pk_bf16_f32 %0, %1, %2" : "=v"(u) : "v"(lo), "v"(hi));
    return u;
}
__device__ __forceinline__ float bflo(unsigned u) {
    union { unsigned x; float f; } c; c.x = u << 16; return c.f;
}
__device__ __forceinline__ float bfhi(unsigned u) {
    union { unsigned x; float f; } c; c.x = u & 0xFFFF0000u; return c.f;
}

// ---------------- k0: pack weights ----------------
__global__ __launch_bounds__(256) void k0_pack_weights(
    const float* __restrict__ gate_w,   // [4][64]
    const float* __restrict__ geom_w,   // [12][64]
    const float* __restrict__ value_w,  // [64][64]
    const float* __restrict__ pw_w,     // [64][256], m = r*64+c
    float* __restrict__ wt16,           // [64][16]
    unsigned short* __restrict__ vwb16, // [4096]
    unsigned short* __restrict__ pwb16) // [64][256] bf16, m' = c*4+r
{
    for (int idx = threadIdx.x; idx < Cc * 16; idx += 256) {
        const int c = idx >> 4, j = idx & 15;
        wt16[idx] = (j < 4) ? gate_w[j * Cc + c] : geom_w[(j - 4) * Cc + c];
    }
    for (int flat = threadIdx.x; flat < 4096; flat += 256) {
        const int t    = flat >> 10;
        const int ks   = (flat >> 9) & 1;
        const int lane = (flat >> 3) & 63;
        const int jj   = flat & 7;
        const int j = t * 16 + (lane & 15);
        const int c = ks * 32 + ((lane >> 4) & 3) * 8 + jj;
        vwb16[flat] = f32_to_bf16(value_w[j * Cc + c]);
    }
    for (int idx = threadIdx.x; idx < Co * 256; idx += 256) {
        const int o = idx >> 8, m = idx & 255;
        const int r = m >> 6, c = m & 63;
        pwb16[o * 256 + c * 4 + r] = f32_to_bf16(pw_w[idx]);
    }
}

__device__ __forceinline__ float softplusf(float v) {
    return v > 20.f ? v : log1pf(__expf(v));
}

// ---------------- k1: hybrid projections, 64 px/block (grid 2048) ----------------
// Thread (ch=tid>>6, px=tid&63) loads its 16 x channels (coalesced in px),
// stages bf16 to LDS, accumulates PARTIAL fp32 gate/geom sums (fp32 required
// for the chaotic theta path); partials reduced through LDS. Epilogue
// distributed across waves, writing the interleaved field record
// fld[B][L][4r][8]: 0:cs2 1:sn2 2:bse 3:pad 4:hyp 5:pad 6:mu 7:pad — each
// wave writes one b64 per rule so all 8 slots (full 128B lines) are covered.
// Value channels via bf16 MFMA, stored as packed bf16 pairs v_pk[B][L][32].
__global__ __launch_bounds__(256) void k1_project(
    const float* __restrict__ x,       // [B][64][L]
    const unsigned short* __restrict__ vwb16,
    const float* __restrict__ wt16,    // [64][16]
    const float* __restrict__ gate_b,  // [4]
    const float* __restrict__ geom_b,  // [12]
    unsigned* __restrict__ v_pk,       // [B][L][32] bf16 pairs
    float* __restrict__ fld)           // [B][L][4][8]
{
    __shared__ unsigned short xb16[64][72];   // 9,216 B
    __shared__ float part[4][64][17];         // 17,408 B; total 26.6 KB

    const int tid  = threadIdx.x;
    const int px   = tid & 63;
    const int ch   = tid >> 6;               // channel-quarter / wave id
    const int lane = tid & 63;
    const int pix0 = blockIdx.x * 64;
    const int b    = pix0 >> 14;
    const int l0   = pix0 & (Ll - 1);

    float acc[16];
#pragma unroll
    for (int j = 0; j < 16; ++j) acc[j] = 0.f;

    const float* xb = x + (size_t)b * Cc * Ll + (l0 + px);
#pragma unroll
    for (int j0 = 0; j0 < 16; j0 += 8) {
        float xv[8];
#pragma unroll
        for (int j = 0; j < 8; ++j) xv[j] = xb[(size_t)(ch * 16 + j0 + j) * Ll];
        uint4 ph;
        unsigned* hp = (unsigned*)&ph;
#pragma unroll
        for (int j = 0; j < 4; ++j)
            hp[j] = cvt_pk_bf16(xv[2 * j], xv[2 * j + 1]);
        *(uint4*)&xb16[px][ch * 16 + j0] = ph;
#pragma unroll
        for (int j = 0; j < 8; ++j) {
            const float* wr = wt16 + (ch * 16 + j0 + j) * 16;   // uniform
#pragma unroll
            for (int jj = 0; jj < 16; ++jj) acc[jj] = fmaf(wr[jj], xv[j], acc[jj]);
        }
    }
#pragma unroll
    for (int jj = 0; jj < 16; ++jj) part[ch][px][jj] = acc[jj];

    // A fragments (value weights) — issue early, consumed after barrier
    short8 af[8];
#pragma unroll
    for (int i = 0; i < 8; ++i)
        af[i] = *(const short8*)(vwb16 + ((size_t)(i * 64 + lane)) * 8);

    __syncthreads();

    // distributed epilogue: wave g handles output group g for all 64 px
    {
        const int g = ch;
        const int l = l0 + px;
        float* fo = fld + ((size_t)b * Ll + l) * 32;   // 4 rules x 8 slots
        float o[4];
#pragma unroll
        for (int q = 0; q < 4; ++q)
            o[q] = part[0][px][4 * g + q] + part[1][px][4 * g + q]
                 + part[2][px][4 * g + q] + part[3][px][4 * g + q];
        if (g == 0) {
            float e[4], gm = -1e30f;
#pragma unroll
            for (int q = 0; q < 4; ++q) { e[q] = o[q] + gate_b[q]; gm = fmaxf(gm, e[q]); }
            float gs = 0.f;
#pragma unroll
            for (int q = 0; q < 4; ++q) { e[q] = __expf(e[q] - gm); gs += e[q]; }
            const float gi = __fdividef(1.f, gs);
#pragma unroll
            for (int q = 0; q < 4; ++q) {
                float2 wv; wv.x = e[q] * gi; wv.y = 0.f;
                *(float2*)(fo + q * 8 + 6) = wv;           // mu
            }
        } else if (g == 1) {
#pragma unroll
            for (int q = 0; q < 4; ++q) {
                float2 wv;
                __sincosf(2.f * (o[q] + geom_b[q]), &wv.y, &wv.x);
                *(float2*)(fo + q * 8 + 0) = wv;           // cs2, sn2
            }
        } else if (g == 2) {
#pragma unroll
            for (int q = 0; q < 4; ++q) {
                float2 wv; wv.x = softplusf(o[q] + geom_b[4 + q]) + 1e-4f; wv.y = 0.f;
                *(float2*)(fo + q * 8 + 2) = wv;           // bse
            }
        } else {
#pragma unroll
            for (int q = 0; q < 4; ++q) {
                float2 wv; wv.x = softplusf(o[q] + geom_b[8 + q]); wv.y = 0.f;
                *(float2*)(fo + q * 8 + 4) = wv;           // hyp
            }
        }
    }

    // value channels via single-bf16 MFMA: wave ch owns p-tile ch
    const int px16 = lane & 15;
    const int g2   = lane >> 4;
    {
        const int row = ch * 16 + px16;
        const short8 bh0 = *(const short8*)&xb16[row][g2 * 8];
        const short8 bh1 = *(const short8*)&xb16[row][32 + g2 * 8];

        f32x4 d0, d1, d2, d3;
#define PROJ_TILE(dst, t)                                              \
        {                                                              \
            f32x4 a_ = {0.f, 0.f, 0.f, 0.f};                           \
            a_ = __builtin_amdgcn_mfma_f32_16x16x32_bf16(af[2*(t)],   bh0, a_, 0, 0, 0); \
            a_ = __builtin_amdgcn_mfma_f32_16x16x32_bf16(af[2*(t)+1], bh1, a_, 0, 0, 0); \
            dst = a_;                                                  \
        }
        PROJ_TILE(d0, 0) PROJ_TILE(d1, 1) PROJ_TILE(d2, 2) PROJ_TILE(d3, 3)
#undef PROJ_TILE

        // lane holds channels c = 16t + 4g2 + q -> pair index 8t + 2g2
        const int l = l0 + ch * 16 + px16;
        unsigned* vp = v_pk + ((size_t)b * Ll + l) * 32 + g2 * 2;
        uint2 u;
        u.x = cvt_pk_bf16(d0[0], d0[1]); u.y = cvt_pk_bf16(d0[2], d0[3]);
        *(uint2*)(vp)      = u;
        u.x = cvt_pk_bf16(d1[0], d1[1]); u.y = cvt_pk_bf16(d1[2], d1[3]);
        *(uint2*)(vp + 8)  = u;
        u.x = cvt_pk_bf16(d2[0], d2[1]); u.y = cvt_pk_bf16(d2[2], d2[3]);
        *(uint2*)(vp + 16) = u;
        u.x = cvt_pk_bf16(d3[0], d3[1]); u.y = cvt_pk_bf16(d3[2], d3[3]);
        *(uint2*)(vp + 24) = u;
    }
}

// ---------------- k23: fused compat + aggregation + MFMA pointwise ----------------
// TP=64 pixels, 4 waves, LDS 39936 B -> 4 blocks/CU. XCD-bijective swizzle.
// Stage A (lane=pixel): thread (px, r=wave) reads interleaved field records
// (2x b128 per neighbor, 18 total) and writes 9 normalized compat weights as
// packed bf16 pairs into wqpk[px][24-uint row] at r*5 (rows 96B, b128-able).
// Stage B (lane=channel): wave w owns px w*16..+15; 54 v-lines unpacked from
// packed bf16; per pixel wq read with 5x ds_read_b128 (broadcast).
// Stage C: MFMA pointwise, A-frags pre-barrier, 4 p-tiles, bias C-init.
__global__ __launch_bounds__(256, 4) void k23_fused(
    const float* __restrict__ fld,           // [B][L][4][8]
    const unsigned* __restrict__ v_pk,       // [B][L][32] bf16 pairs
    const unsigned short* __restrict__ pwb16,// [64][256] bf16, m'-order
    const float* __restrict__ pw_b,          // [64]
    float* __restrict__ out)                 // [B][64][L]
{
    __shared__ unsigned wqpk[64 * 24];       // 6,144 B
    __shared__ unsigned short agg[TP][264];  // 33,792 B

    const int tid = threadIdx.x;
    const int cpx = (int)(gridDim.x >> 3);   // 256
    const int bid = (int)((blockIdx.x & 7) * cpx + (blockIdx.x >> 3));
    const int pix0 = bid * TP;
    const int b = pix0 >> 14;
    const int l0 = pix0 & (Ll - 1);

    // ---- stage A: lane = pixel ----
    {
        const int px = tid & 63;
        const int r  = tid >> 6;
        const int l  = l0 + px;
        const int hr = l >> 7;
        const int wc = l & (Ww - 1);
        const float* fbase = fld + (size_t)b * Ll * 32 + r * 8;

        const float* fc = fbase + (size_t)l * 32;
        const f32x4 c0 = *(const f32x4*)fc;        // cs2, sn2, bse, pad
        const f32x4 c1 = *(const f32x4*)(fc + 4);  // hyp, pad, mu, pad
        const float cc = c0[0], sc = c0[1], bc = c0[2], yc = c1[0], mc = c1[2];

        float cmp[9];
        float sum = 0.f;
#pragma unroll
        for (int s = 0; s < 9; ++s) {
            const int dy = s / 3 - 1, dx = s % 3 - 1;
            float cv;
            if (dx == 0 && dy == 0) {
                cv = mc;
            } else {
                const int hh = hr + dy, ww = wc + dx;
                const int hcl = min(max(hh, 0), Hh - 1);
                const int wcl = min(max(ww, 0), Ww - 1);
                const bool inb = ((unsigned)hh < (unsigned)Hh) &
                                 ((unsigned)ww < (unsigned)Ww);
                const float* fn = fbase + (size_t)(hcl * Ww + wcl) * 32;
                const f32x4 n0 = *(const f32x4*)fn;
                const f32x4 n1 = *(const f32x4*)(fn + 4);
                const float cn = n0[0], sn = n0[1], bn = n0[2], yn = n1[0];
                const float mun = inb ? n1[2] : 0.f;
                const float c2 = cc + cn, s2 = sc + sn;
                const float h = sqrtf(fmaxf(c2 * c2 + s2 * s2, 1e-24f));
                const float rh = __fdividef(0.5f, h);
                float pu2, ps2;
                if (dx != 0 && dy != 0) {              // diagonal
                    const float t = 2.f * (float)(dx * dy) * (s2 * rh);
                    pu2 = 1.f + t; ps2 = 1.f - t;
                } else if (dx != 0) {                  // horizontal
                    pu2 = 0.5f + c2 * rh; ps2 = 0.5f - c2 * rh;
                } else {                               // vertical
                    pu2 = 0.5f - c2 * rh; ps2 = 0.5f + c2 * rh;
                }
                const float bp = 0.5f * (bc + bn);
                const float hp = 0.5f * (yc + yn);
                const float E = __expf(hp);
                const float iu = __fdividef(1.f, bp * E);   // 1/sigma_u
                const float is = E * E * iu;                // 1/sigma_s
                const float q = pu2 * (iu * iu) + ps2 * (is * is);
                cv = __expf(-q) * mun;
            }
            cmp[s] = cv;
            sum += cv;
        }
        const float inv = __fdividef(1.f, sum + 1e-6f);
        unsigned* wrow = &wqpk[px * 24 + r * 5];
#pragma unroll
        for (int k = 0; k < 4; ++k)
            wrow[k] = cvt_pk_bf16(cmp[2 * k] * inv, cmp[2 * k + 1] * inv);
        wrow[4] = cvt_pk_bf16(cmp[8] * inv, 0.f);
    }
    __syncthreads();

    // ---- stage B: lane = channel ----
    const int w = tid >> 6, c = tid & 63;
    {
        const int hr0  = l0 >> 7;
        const int rows[3] = { max(hr0 - 1, 0) * Ww, hr0 * Ww, min(hr0 + 1, Hh - 1) * Ww };
        const int colbase = (l0 & (Ww - 1)) + w * 16;
        const unsigned* vb = v_pk + (size_t)b * Ll * 32 + (c >> 1);
        const int hi = c & 1;

        float vv[3][18];
#pragma unroll
        for (int ry = 0; ry < 3; ++ry)
#pragma unroll
            for (int cx = 0; cx < 18; ++cx) {
                const int col = min(max(colbase + cx - 1, 0), Ww - 1);
                const unsigned u = vb[(size_t)(rows[ry] + col) * 32];
                vv[ry][cx] = hi ? bfhi(u) : bflo(u);
            }

#pragma unroll
        for (int p = 0; p < 16; ++p) {
            const unsigned* wrow = &wqpk[(w * 16 + p) * 24];
            unsigned wu[20];
            *(uint4*)(wu)      = *(const uint4*)(wrow);
            *(uint4*)(wu + 4)  = *(const uint4*)(wrow + 4);
            *(uint4*)(wu + 8)  = *(const uint4*)(wrow + 8);
            *(uint4*)(wu + 12) = *(const uint4*)(wrow + 12);
            *(uint4*)(wu + 16) = *(const uint4*)(wrow + 16);
            float av[4];
#pragma unroll
            for (int r = 0; r < 4; ++r) {
                const unsigned u0 = wu[5 * r], u1 = wu[5 * r + 1],
                               u2 = wu[5 * r + 2], u3 = wu[5 * r + 3],
                               u4 = wu[5 * r + 4];
                float a;
                a = bflo(u0) * vv[0][p];
                a = fmaf(bfhi(u0), vv[0][p + 1], a);
                a = fmaf(bflo(u1), vv[0][p + 2], a);
                a = fmaf(bfhi(u1), vv[1][p],     a);
                a = fmaf(bflo(u2), vv[1][p + 1], a);
                a = fmaf(bfhi(u2), vv[1][p + 2], a);
                a = fmaf(bflo(u3), vv[2][p],     a);
                a = fmaf(bfhi(u3), vv[2][p + 1], a);
                a = fmaf(bflo(u4), vv[2][p + 2], a);
                av[r] = a;
            }
            uint2 u;
            u.x = cvt_pk_bf16(av[0], av[1]);
            u.y = cvt_pk_bf16(av[2], av[3]);
            *((uint2*)(&agg[w * 16 + p][0]) + c) = u;   // m' = c*4+r
        }
    }

    // A fragments: issue before the barrier (in flight across it)
    const int ar    = tid & 15;
    const int chunk = (tid >> 4) & 3;
    const int o0    = w * 16;
    const unsigned short* aPtr = pwb16 + (o0 + ar) * 256 + chunk * 8;
    short8 af[8];
#pragma unroll
    for (int kt = 0; kt < 8; ++kt) af[kt] = *(const short8*)(aPtr + kt * 32);

    __syncthreads();

    // ---- stage C: MFMA pointwise, 4 p-tiles, A reused ----
    f32x4 d0, d1, d2, d3;
#pragma unroll
    for (int q = 0; q < 4; ++q) {
        const float bv = pw_b[o0 + chunk * 4 + q];
        d0[q] = bv; d1[q] = bv; d2[q] = bv; d3[q] = bv;
    }
    const unsigned short* b0 = &agg[ 0 + ar][chunk * 8];
    const unsigned short* b1 = &agg[16 + ar][chunk * 8];
    const unsigned short* b2 = &agg[32 + ar][chunk * 8];
    const unsigned short* b3 = &agg[48 + ar][chunk * 8];
#pragma unroll
    for (int kt = 0; kt < 8; ++kt) {
        d0 = __builtin_amdgcn_mfma_f32_16x16x32_bf16(af[kt], *(const short8*)(b0 + kt * 32), d0, 0, 0, 0);
        d1 = __builtin_amdgcn_mfma_f32_16x16x32_bf16(af[kt], *(const short8*)(b1 + kt * 32), d1, 0, 0, 0);
        d2 = __builtin_amdgcn_mfma_f32_16x16x32_bf16(af[kt], *(const short8*)(b2 + kt * 32), d2, 0, 0, 0);
        d3 = __builtin_amdgcn_mfma_f32_16x16x32_bf16(af[kt], *(const short8*)(b3 + kt * 32), d3, 0, 0, 0);
    }

#pragma unroll
    for (int q = 0; q < 4; ++q) {
        const int o = o0 + chunk * 4 + q;
        float* ob = out + ((size_t)b * Co + o) * Ll + l0 + ar;
        ob[0]  = d0[q];
        ob[16] = d1[q];
        ob[32] = d2[q];
        ob[48] = d3[q];
    }
}

// ---------------- launch ----------------
extern "C" void kernel_launch(void* const* d_in, const int* in_sizes, int n_in,
                              void* d_out, int out_size, void* d_ws, size_t ws_size,
                              hipStream_t stream)
{
    const float* x       = (const float*)d_in[0];
    const float* gate_w  = (const float*)d_in[1];
    const float* gate_b  = (const float*)d_in[2];
    const float* value_w = (const float*)d_in[3];
    const float* geom_w  = (const float*)d_in[4];
    const float* geom_b  = (const float*)d_in[5];
    const float* pw_w    = (const float*)d_in[6];
    const float* pw_b    = (const float*)d_in[7];
    float* out = (float*)d_out;

    unsigned* v_pk = (unsigned*)d_ws;                        // B*L*32 u  (16MB)
    float* fld  = (float*)(v_pk + (size_t)Bx * Ll * 32);     // B*L*32 f  (16MB)
    float* wt16 = fld + (size_t)Bx * Ll * 32;                // 1024 f
    unsigned short* vwb16 = (unsigned short*)(wt16 + 1024);  // 4096 us
    unsigned short* pwb16 = vwb16 + 4096;                    // 16384 us
    // total ws: ~32 MB

    k0_pack_weights<<<1, 256, 0, stream>>>(gate_w, geom_w, value_w, pw_w,
                                           wt16, vwb16, pwb16);
    k1_project<<<NPIX / 64, 256, 0, stream>>>(x, vwb16, wt16, gate_b, geom_b,
                                              v_pk, fld);
    k23_fused<<<NPIX / TP, 256, 0, stream>>>(fld, v_pk, pwb16, pw_b, out);
}

// Round 14
// 73.423 us; speedup vs baseline: 1.2769x; 1.2769x over previous
//
#include <hip/hip_runtime.h>

namespace {
constexpr int Bx = 8, Cc = 64, Hh = 128, Ww = 128, Co = 64;
constexpr int Ll = Hh * Ww;        // 16384 = 2^14
constexpr int NPIX = Bx * Ll;      // 131072
constexpr int TP = 64;             // pixels per block in k23
}

using short8 = __attribute__((ext_vector_type(8))) short;
using f32x4  = __attribute__((ext_vector_type(4))) float;
#if __has_builtin(__builtin_amdgcn_fdot2_f32_bf16)
#define HAVE_DOT2 1
typedef __attribute__((ext_vector_type(2))) __bf16 bf16x2;
__device__ __forceinline__ bf16x2 as_bf16x2(unsigned u) {
    union { unsigned x; bf16x2 v; } c; c.x = u; return c.v;
}
#else
#define HAVE_DOT2 0
#endif

__device__ __forceinline__ unsigned short f32_to_bf16(float f) {
    union { float f; unsigned u; } un; un.f = f;
    unsigned r = un.u + 0x7FFFu + ((un.u >> 16) & 1u);   // round-to-nearest-even
    return (unsigned short)(r >> 16);
}
// packed pair via HW converter (RNE); no builtin on gfx950 -> inline asm
__device__ __forceinline__ unsigned cvt_pk_bf16(float lo, float hi) {
    unsigned u;
    asm("v_cvt_pk_bf16_f32 %0, %1, %2" : "=v"(u) : "v"(lo), "v"(hi));
    return u;
}
__device__ __forceinline__ float bflo(unsigned u) {
    union { unsigned x; float f; } c; c.x = u << 16; return c.f;
}
__device__ __forceinline__ float bfhi(unsigned u) {
    union { unsigned x; float f; } c; c.x = u & 0xFFFF0000u; return c.f;
}

// ---------------- k0: pack weights ----------------
__global__ __launch_bounds__(256) void k0_pack_weights(
    const float* __restrict__ gate_w,   // [4][64]
    const float* __restrict__ geom_w,   // [12][64]
    const float* __restrict__ value_w,  // [64][64]
    const float* __restrict__ pw_w,     // [64][256], m = r*64+c
    float* __restrict__ wt16,           // [64][16]
    unsigned short* __restrict__ vwb16, // [4096]
    unsigned short* __restrict__ pwb16) // [64][256] bf16, m' = c*4+r
{
    for (int idx = threadIdx.x; idx < Cc * 16; idx += 256) {
        const int c = idx >> 4, j = idx & 15;
        wt16[idx] = (j < 4) ? gate_w[j * Cc + c] : geom_w[(j - 4) * Cc + c];
    }
    for (int flat = threadIdx.x; flat < 4096; flat += 256) {
        const int t    = flat >> 10;
        const int ks   = (flat >> 9) & 1;
        const int lane = (flat >> 3) & 63;
        const int jj   = flat & 7;
        const int j = t * 16 + (lane & 15);
        const int c = ks * 32 + ((lane >> 4) & 3) * 8 + jj;
        vwb16[flat] = f32_to_bf16(value_w[j * Cc + c]);
    }
    for (int idx = threadIdx.x; idx < Co * 256; idx += 256) {
        const int o = idx >> 8, m = idx & 255;
        const int r = m >> 6, c = m & 63;
        pwb16[o * 256 + c * 4 + r] = f32_to_bf16(pw_w[idx]);
    }
}

__device__ __forceinline__ float softplusf(float v) {
    return v > 20.f ? v : log1pf(__expf(v));
}

// ---------------- k1: hybrid projections, 64 px/block (grid 2048) ----------------
// (identical to R12's k1: planar field outputs, fp32 pixel-major v)
__global__ __launch_bounds__(256) void k1_project(
    const float* __restrict__ x,       // [B][64][L]
    const unsigned short* __restrict__ vwb16,
    const float* __restrict__ wt16,    // [64][16]
    const float* __restrict__ gate_b,  // [4]
    const float* __restrict__ geom_b,  // [12]
    float* __restrict__ v,             // [B][L][64]  (pixel-major)
    float* __restrict__ mu,            // [B][4][L]
    float* __restrict__ cs2, float* __restrict__ sn2,
    float* __restrict__ bse, float* __restrict__ hyp)  // each [B][4][L]
{
    __shared__ unsigned short xb16[64][72];   // 9,216 B
    __shared__ float part[4][64][17];         // 17,408 B; total 26.6 KB

    const int tid  = threadIdx.x;
    const int px   = tid & 63;
    const int ch   = tid >> 6;               // channel-quarter / wave id
    const int lane = tid & 63;
    const int pix0 = blockIdx.x * 64;
    const int b    = pix0 >> 14;
    const int l0   = pix0 & (Ll - 1);

    float acc[16];
#pragma unroll
    for (int j = 0; j < 16; ++j) acc[j] = 0.f;

    const float* xb = x + (size_t)b * Cc * Ll + (l0 + px);
#pragma unroll
    for (int j0 = 0; j0 < 16; j0 += 8) {
        float xv[8];
#pragma unroll
        for (int j = 0; j < 8; ++j) xv[j] = xb[(size_t)(ch * 16 + j0 + j) * Ll];
        uint4 ph;
        unsigned* hp = (unsigned*)&ph;
#pragma unroll
        for (int j = 0; j < 4; ++j)
            hp[j] = cvt_pk_bf16(xv[2 * j], xv[2 * j + 1]);
        *(uint4*)&xb16[px][ch * 16 + j0] = ph;
#pragma unroll
        for (int j = 0; j < 8; ++j) {
            const float* wr = wt16 + (ch * 16 + j0 + j) * 16;   // uniform
#pragma unroll
            for (int jj = 0; jj < 16; ++jj) acc[jj] = fmaf(wr[jj], xv[j], acc[jj]);
        }
    }
#pragma unroll
    for (int jj = 0; jj < 16; ++jj) part[ch][px][jj] = acc[jj];

    short8 af[8];
#pragma unroll
    for (int i = 0; i < 8; ++i)
        af[i] = *(const short8*)(vwb16 + ((size_t)(i * 64 + lane)) * 8);

    __syncthreads();

    {
        const int g = ch;
        const int l = l0 + px;
        const size_t fb = (size_t)b * 4 * Ll + l;
        float o[4];
#pragma unroll
        for (int q = 0; q < 4; ++q)
            o[q] = part[0][px][4 * g + q] + part[1][px][4 * g + q]
                 + part[2][px][4 * g + q] + part[3][px][4 * g + q];
        if (g == 0) {
            float e[4], gm = -1e30f;
#pragma unroll
            for (int q = 0; q < 4; ++q) { e[q] = o[q] + gate_b[q]; gm = fmaxf(gm, e[q]); }
            float gs = 0.f;
#pragma unroll
            for (int q = 0; q < 4; ++q) { e[q] = __expf(e[q] - gm); gs += e[q]; }
            const float gi = __fdividef(1.f, gs);
#pragma unroll
            for (int q = 0; q < 4; ++q) mu[fb + (size_t)q * Ll] = e[q] * gi;
        } else if (g == 1) {
#pragma unroll
            for (int q = 0; q < 4; ++q) {
                float sv, cv;
                __sincosf(2.f * (o[q] + geom_b[q]), &sv, &cv);
                cs2[fb + (size_t)q * Ll] = cv;
                sn2[fb + (size_t)q * Ll] = sv;
            }
        } else if (g == 2) {
#pragma unroll
            for (int q = 0; q < 4; ++q)
                bse[fb + (size_t)q * Ll] = softplusf(o[q] + geom_b[4 + q]) + 1e-4f;
        } else {
#pragma unroll
            for (int q = 0; q < 4; ++q)
                hyp[fb + (size_t)q * Ll] = softplusf(o[q] + geom_b[8 + q]);
        }
    }

    const int px16 = lane & 15;
    const int g2   = lane >> 4;
    {
        const int row = ch * 16 + px16;
        const short8 bh0 = *(const short8*)&xb16[row][g2 * 8];
        const short8 bh1 = *(const short8*)&xb16[row][32 + g2 * 8];

        f32x4 d0, d1, d2, d3;
#define PROJ_TILE(dst, t)                                              \
        {                                                              \
            f32x4 a_ = {0.f, 0.f, 0.f, 0.f};                           \
            a_ = __builtin_amdgcn_mfma_f32_16x16x32_bf16(af[2*(t)],   bh0, a_, 0, 0, 0); \
            a_ = __builtin_amdgcn_mfma_f32_16x16x32_bf16(af[2*(t)+1], bh1, a_, 0, 0, 0); \
            dst = a_;                                                  \
        }
        PROJ_TILE(d0, 0) PROJ_TILE(d1, 1) PROJ_TILE(d2, 2) PROJ_TILE(d3, 3)
#undef PROJ_TILE

        const int l = l0 + ch * 16 + px16;
        float* vrow = v + ((size_t)b * Ll + l) * 64 + g2 * 4;
        *(f32x4*)(vrow)      = d0;
        *(f32x4*)(vrow + 16) = d1;
        *(f32x4*)(vrow + 32) = d2;
        *(f32x4*)(vrow + 48) = d3;
    }
}

// ---------------- k23: fused compat + aggregation + MFMA pointwise ----------------
// R12 structure (planar fields, fp32 v, wqpk[4][64][6], XCD swizzle, 4 blk/CU).
// Stage A packs wq in ROW-PAIR order per rule: (s0,s1)(s3,s4)(s6,s7)(s2,s5)(s8,-).
// Stage B uses v_dot2_f32_bf16 on pre-packed v column pairs:
//   pk0/pk1/pk2[cx] = (vv[ry][cx], vv[ry][cx+1]); pkx[cx-2] = (vv0[cx], vv1[cx]).
//   per (px,r): 4 dot2 + 1 fma + 1 unpack (vs ~18 inst unpack+fma).
__global__ __launch_bounds__(256, 4) void k23_fused(
    const float* __restrict__ mu,
    const float* __restrict__ cs2, const float* __restrict__ sn2,
    const float* __restrict__ bse, const float* __restrict__ hyp,
    const float* __restrict__ v,             // [B][L][64]
    const unsigned short* __restrict__ pwb16,// [64][256] bf16, m'-order
    const float* __restrict__ pw_b,          // [64]
    float* __restrict__ out)                 // [B][64][L]
{
    __shared__ unsigned wqpk[4][64][6];      // 6,144 B
    __shared__ unsigned short agg[TP][264];  // 33,792 B

    const int tid = threadIdx.x;
    const int cpx = (int)(gridDim.x >> 3);   // 256
    const int bid = (int)((blockIdx.x & 7) * cpx + (blockIdx.x >> 3));
    const int pix0 = bid * TP;
    const int b = pix0 >> 14;
    const int l0 = pix0 & (Ll - 1);

    // ---- stage A: lane = pixel ----
    {
        const int px = tid & 63;
        const int r  = tid >> 6;
        const int l  = l0 + px;
        const int hr = l >> 7;
        const int wc = l & (Ww - 1);
        const size_t fb = ((size_t)b * 4 + r) * Ll;

        const float cc = cs2[fb + l], sc = sn2[fb + l];
        const float bc = bse[fb + l], yc = hyp[fb + l];
        const float mc = mu[fb + l];

        float cmp[9];
        float sum = 0.f;
#pragma unroll
        for (int s = 0; s < 9; ++s) {
            const int dy = s / 3 - 1, dx = s % 3 - 1;
            float cv;
            if (dx == 0 && dy == 0) {
                cv = mc;
            } else {
                const int hh = hr + dy, ww = wc + dx;
                const int hcl = min(max(hh, 0), Hh - 1);
                const int wcl = min(max(ww, 0), Ww - 1);
                const bool inb = ((unsigned)hh < (unsigned)Hh) &
                                 ((unsigned)ww < (unsigned)Ww);
                const size_t ni = fb + hcl * Ww + wcl;
                const float cn = cs2[ni], sn = sn2[ni];
                const float bn = bse[ni], yn = hyp[ni];
                const float mun = inb ? mu[ni] : 0.f;
                const float c2 = cc + cn, s2 = sc + sn;
                const float h = sqrtf(fmaxf(c2 * c2 + s2 * s2, 1e-24f));
                const float rh = __fdividef(0.5f, h);
                float pu2, ps2;
                if (dx != 0 && dy != 0) {              // diagonal
                    const float t = 2.f * (float)(dx * dy) * (s2 * rh);
                    pu2 = 1.f + t; ps2 = 1.f - t;
                } else if (dx != 0) {                  // horizontal
                    pu2 = 0.5f + c2 * rh; ps2 = 0.5f - c2 * rh;
                } else {                               // vertical
                    pu2 = 0.5f - c2 * rh; ps2 = 0.5f + c2 * rh;
                }
                const float bp = 0.5f * (bc + bn);
                const float hp = 0.5f * (yc + yn);
                const float E = __expf(hp);
                const float iu = __fdividef(1.f, bp * E);   // 1/sigma_u
                const float is = E * E * iu;                // 1/sigma_s
                const float q = pu2 * (iu * iu) + ps2 * (is * is);
                cv = __expf(-q) * mun;
            }
            cmp[s] = cv;
            sum += cv;
        }
        const float inv = __fdividef(1.f, sum + 1e-6f);
        unsigned* wrow = &wqpk[r][px][0];
        wrow[0] = cvt_pk_bf16(cmp[0] * inv, cmp[1] * inv);  // s0,s1
        wrow[1] = cvt_pk_bf16(cmp[3] * inv, cmp[4] * inv);  // s3,s4
        wrow[2] = cvt_pk_bf16(cmp[6] * inv, cmp[7] * inv);  // s6,s7
        wrow[3] = cvt_pk_bf16(cmp[2] * inv, cmp[5] * inv);  // s2,s5
        wrow[4] = cvt_pk_bf16(cmp[8] * inv, 0.f);           // s8
    }
    __syncthreads();

    // ---- stage B: lane = channel ----
    const int w = tid >> 6, c = tid & 63;
    {
        const int hr0  = l0 >> 7;
        const int rows[3] = { max(hr0 - 1, 0) * Ww, hr0 * Ww, min(hr0 + 1, Hh - 1) * Ww };
        const int colbase = (l0 & (Ww - 1)) + w * 16;
        const float* vb = v + ((size_t)b * Ll) * 64 + c;

        float vv[3][18];
#pragma unroll
        for (int ry = 0; ry < 3; ++ry)
#pragma unroll
            for (int cx = 0; cx < 18; ++cx) {
                const int col = min(max(colbase + cx - 1, 0), Ww - 1);
                vv[ry][cx] = vb[(size_t)(rows[ry] + col) * 64];
            }

#if HAVE_DOT2
        unsigned pk0[17], pk1[17], pk2[17], pkx[16];
#pragma unroll
        for (int cx = 0; cx < 17; ++cx) {
            pk0[cx] = cvt_pk_bf16(vv[0][cx], vv[0][cx + 1]);
            pk1[cx] = cvt_pk_bf16(vv[1][cx], vv[1][cx + 1]);
            pk2[cx] = cvt_pk_bf16(vv[2][cx], vv[2][cx + 1]);
        }
#pragma unroll
        for (int cx = 0; cx < 16; ++cx)
            pkx[cx] = cvt_pk_bf16(vv[0][cx + 2], vv[1][cx + 2]);
#endif

#pragma unroll
        for (int p = 0; p < 16; ++p) {
            float av[4];
#pragma unroll
            for (int r = 0; r < 4; ++r) {
                const unsigned* wrow = &wqpk[r][w * 16 + p][0];
                const unsigned u0 = wrow[0], u1 = wrow[1], u2 = wrow[2],
                               u3 = wrow[3], u4 = wrow[4];
#if HAVE_DOT2
                float a;
                a = __builtin_amdgcn_fdot2_f32_bf16(as_bf16x2(u0), as_bf16x2(pk0[p]), 0.f, false);
                a = __builtin_amdgcn_fdot2_f32_bf16(as_bf16x2(u1), as_bf16x2(pk1[p]), a, false);
                a = __builtin_amdgcn_fdot2_f32_bf16(as_bf16x2(u2), as_bf16x2(pk2[p]), a, false);
                a = __builtin_amdgcn_fdot2_f32_bf16(as_bf16x2(u3), as_bf16x2(pkx[p]), a, false);
                a = fmaf(bflo(u4), vv[2][p + 2], a);
#else
                float a;
                a = bflo(u0) * vv[0][p];                 // s0
                a = fmaf(bfhi(u0), vv[0][p + 1], a);     // s1
                a = fmaf(bflo(u3), vv[0][p + 2], a);     // s2
                a = fmaf(bflo(u1), vv[1][p],     a);     // s3
                a = fmaf(bfhi(u1), vv[1][p + 1], a);     // s4
                a = fmaf(bfhi(u3), vv[1][p + 2], a);     // s5
                a = fmaf(bflo(u2), vv[2][p],     a);     // s6
                a = fmaf(bfhi(u2), vv[2][p + 1], a);     // s7
                a = fmaf(bflo(u4), vv[2][p + 2], a);     // s8
#endif
                av[r] = a;
            }
            uint2 u;
            u.x = cvt_pk_bf16(av[0], av[1]);
            u.y = cvt_pk_bf16(av[2], av[3]);
            *((uint2*)(&agg[w * 16 + p][0]) + c) = u;   // m' = c*4+r
        }
    }

    // A fragments: issue before the barrier (in flight across it)
    const int ar    = tid & 15;
    const int chunk = (tid >> 4) & 3;
    const int o0    = w * 16;
    const unsigned short* aPtr = pwb16 + (o0 + ar) * 256 + chunk * 8;
    short8 af[8];
#pragma unroll
    for (int kt = 0; kt < 8; ++kt) af[kt] = *(const short8*)(aPtr + kt * 32);

    __syncthreads();

    // ---- stage C: MFMA pointwise, 4 p-tiles, A reused ----
    f32x4 d0, d1, d2, d3;
#pragma unroll
    for (int q = 0; q < 4; ++q) {
        const float bv = pw_b[o0 + chunk * 4 + q];
        d0[q] = bv; d1[q] = bv; d2[q] = bv; d3[q] = bv;
    }
    const unsigned short* b0 = &agg[ 0 + ar][chunk * 8];
    const unsigned short* b1 = &agg[16 + ar][chunk * 8];
    const unsigned short* b2 = &agg[32 + ar][chunk * 8];
    const unsigned short* b3 = &agg[48 + ar][chunk * 8];
#pragma unroll
    for (int kt = 0; kt < 8; ++kt) {
        d0 = __builtin_amdgcn_mfma_f32_16x16x32_bf16(af[kt], *(const short8*)(b0 + kt * 32), d0, 0, 0, 0);
        d1 = __builtin_amdgcn_mfma_f32_16x16x32_bf16(af[kt], *(const short8*)(b1 + kt * 32), d1, 0, 0, 0);
        d2 = __builtin_amdgcn_mfma_f32_16x16x32_bf16(af[kt], *(const short8*)(b2 + kt * 32), d2, 0, 0, 0);
        d3 = __builtin_amdgcn_mfma_f32_16x16x32_bf16(af[kt], *(const short8*)(b3 + kt * 32), d3, 0, 0, 0);
    }

#pragma unroll
    for (int q = 0; q < 4; ++q) {
        const int o = o0 + chunk * 4 + q;
        float* ob = out + ((size_t)b * Co + o) * Ll + l0 + ar;
        ob[0]  = d0[q];
        ob[16] = d1[q];
        ob[32] = d2[q];
        ob[48] = d3[q];
    }
}

// ---------------- launch ----------------
extern "C" void kernel_launch(void* const* d_in, const int* in_sizes, int n_in,
                              void* d_out, int out_size, void* d_ws, size_t ws_size,
                              hipStream_t stream)
{
    const float* x       = (const float*)d_in[0];
    const float* gate_w  = (const float*)d_in[1];
    const float* gate_b  = (const float*)d_in[2];
    const float* value_w = (const float*)d_in[3];
    const float* geom_w  = (const float*)d_in[4];
    const float* geom_b  = (const float*)d_in[5];
    const float* pw_w    = (const float*)d_in[6];
    const float* pw_b    = (const float*)d_in[7];
    float* out = (float*)d_out;

    float* ws  = (float*)d_ws;
    float* v    = ws;                                  // B*L*64   = 8388608
    float* mu   = v    + (size_t)Bx * Ll * 64;         // B*4*L    = 524288
    float* cs2  = mu   + (size_t)Bx * 4 * Ll;
    float* sn2  = cs2  + (size_t)Bx * 4 * Ll;
    float* bse  = sn2  + (size_t)Bx * 4 * Ll;
    float* hyp  = bse  + (size_t)Bx * 4 * Ll;
    float* wt16 = hyp  + (size_t)Bx * 4 * Ll;                 // 1024 f
    unsigned short* vwb16 = (unsigned short*)(wt16 + 1024);   // 4096 us
    unsigned short* pwb16 = vwb16 + 4096;                     // 16384 us
    // total ws: ~44 MB

    k0_pack_weights<<<1, 256, 0, stream>>>(gate_w, geom_w, value_w, pw_w,
                                           wt16, vwb16, pwb16);
    k1_project<<<NPIX / 64, 256, 0, stream>>>(x, vwb16, wt16, gate_b, geom_b,
                                              v, mu, cs2, sn2, bse, hyp);
    k23_fused<<<NPIX / TP, 256, 0, stream>>>(mu, cs2, sn2, bse, hyp,
                                             v, pwb16, pw_b, out);
}

// Round 15
// 70.376 us; speedup vs baseline: 1.3322x; 1.0433x over previous
//
#include <hip/hip_runtime.h>

namespace {
constexpr int Bx = 8, Cc = 64, Hh = 128, Ww = 128, Co = 64;
constexpr int Ll = Hh * Ww;        // 16384 = 2^14
constexpr int NPIX = Bx * Ll;      // 131072
constexpr int TP = 32;             // pixels per block in k23
}

using short8 = __attribute__((ext_vector_type(8))) short;
using f32x4  = __attribute__((ext_vector_type(4))) float;

__device__ __forceinline__ unsigned short f32_to_bf16(float f) {
    union { float f; unsigned u; } un; un.f = f;
    unsigned r = un.u + 0x7FFFu + ((un.u >> 16) & 1u);   // round-to-nearest-even
    return (unsigned short)(r >> 16);
}
// packed pair via HW converter (RNE); no builtin on gfx950 -> inline asm
__device__ __forceinline__ unsigned cvt_pk_bf16(float lo, float hi) {
    unsigned u;
    asm("v_cvt_pk_bf16_f32 %0, %1, %2" : "=v"(u) : "v"(lo), "v"(hi));
    return u;
}
__device__ __forceinline__ float bflo(unsigned u) {
    union { unsigned x; float f; } c; c.x = u << 16; return c.f;
}
__device__ __forceinline__ float bfhi(unsigned u) {
    union { unsigned x; float f; } c; c.x = u & 0xFFFF0000u; return c.f;
}

// ---------------- k0: pack weights (8 blocks) ----------------
__global__ __launch_bounds__(256) void k0_pack_weights(
    const float* __restrict__ gate_w,   // [4][64]
    const float* __restrict__ geom_w,   // [12][64]
    const float* __restrict__ value_w,  // [64][64]
    const float* __restrict__ pw_w,     // [64][256], m = r*64+c
    float* __restrict__ wt16,           // [64][16]
    unsigned short* __restrict__ vwb16, // [4096]
    unsigned short* __restrict__ pwb16) // [64][256] bf16, m' = c*4+r
{
    const int tid0 = blockIdx.x * 256 + threadIdx.x;
    for (int idx = tid0; idx < Cc * 16; idx += 2048) {
        const int c = idx >> 4, j = idx & 15;
        wt16[idx] = (j < 4) ? gate_w[j * Cc + c] : geom_w[(j - 4) * Cc + c];
    }
    for (int flat = tid0; flat < 4096; flat += 2048) {
        const int t    = flat >> 10;
        const int ks   = (flat >> 9) & 1;
        const int lane = (flat >> 3) & 63;
        const int jj   = flat & 7;
        const int j = t * 16 + (lane & 15);
        const int c = ks * 32 + ((lane >> 4) & 3) * 8 + jj;
        vwb16[flat] = f32_to_bf16(value_w[j * Cc + c]);
    }
    for (int idx = tid0; idx < Co * 256; idx += 2048) {
        const int o = idx >> 8, m = idx & 255;
        const int r = m >> 6, c = m & 63;
        pwb16[o * 256 + c * 4 + r] = f32_to_bf16(pw_w[idx]);
    }
}

__device__ __forceinline__ float softplusf(float v) {
    return v > 20.f ? v : log1pf(__expf(v));
}

// ---------------- k1: hybrid projections, 64 px/block (grid 2048) ----------------
// (unchanged from R12/R14: planar field outputs, fp32 pixel-major v)
__global__ __launch_bounds__(256) void k1_project(
    const float* __restrict__ x,       // [B][64][L]
    const unsigned short* __restrict__ vwb16,
    const float* __restrict__ wt16,    // [64][16]
    const float* __restrict__ gate_b,  // [4]
    const float* __restrict__ geom_b,  // [12]
    float* __restrict__ v,             // [B][L][64]  (pixel-major)
    float* __restrict__ mu,            // [B][4][L]
    float* __restrict__ cs2, float* __restrict__ sn2,
    float* __restrict__ bse, float* __restrict__ hyp)  // each [B][4][L]
{
    __shared__ unsigned short xb16[64][72];   // 9,216 B
    __shared__ float part[4][64][17];         // 17,408 B; total 26.6 KB

    const int tid  = threadIdx.x;
    const int px   = tid & 63;
    const int ch   = tid >> 6;               // channel-quarter / wave id
    const int lane = tid & 63;
    const int pix0 = blockIdx.x * 64;
    const int b    = pix0 >> 14;
    const int l0   = pix0 & (Ll - 1);

    float acc[16];
#pragma unroll
    for (int j = 0; j < 16; ++j) acc[j] = 0.f;

    const float* xb = x + (size_t)b * Cc * Ll + (l0 + px);
#pragma unroll
    for (int j0 = 0; j0 < 16; j0 += 8) {
        float xv[8];
#pragma unroll
        for (int j = 0; j < 8; ++j) xv[j] = xb[(size_t)(ch * 16 + j0 + j) * Ll];
        uint4 ph;
        unsigned* hp = (unsigned*)&ph;
#pragma unroll
        for (int j = 0; j < 4; ++j)
            hp[j] = cvt_pk_bf16(xv[2 * j], xv[2 * j + 1]);
        *(uint4*)&xb16[px][ch * 16 + j0] = ph;
#pragma unroll
        for (int j = 0; j < 8; ++j) {
            const float* wr = wt16 + (ch * 16 + j0 + j) * 16;   // uniform
#pragma unroll
            for (int jj = 0; jj < 16; ++jj) acc[jj] = fmaf(wr[jj], xv[j], acc[jj]);
        }
    }
#pragma unroll
    for (int jj = 0; jj < 16; ++jj) part[ch][px][jj] = acc[jj];

    short8 af[8];
#pragma unroll
    for (int i = 0; i < 8; ++i)
        af[i] = *(const short8*)(vwb16 + ((size_t)(i * 64 + lane)) * 8);

    __syncthreads();

    {
        const int g = ch;
        const int l = l0 + px;
        const size_t fb = (size_t)b * 4 * Ll + l;
        float o[4];
#pragma unroll
        for (int q = 0; q < 4; ++q)
            o[q] = part[0][px][4 * g + q] + part[1][px][4 * g + q]
                 + part[2][px][4 * g + q] + part[3][px][4 * g + q];
        if (g == 0) {
            float e[4], gm = -1e30f;
#pragma unroll
            for (int q = 0; q < 4; ++q) { e[q] = o[q] + gate_b[q]; gm = fmaxf(gm, e[q]); }
            float gs = 0.f;
#pragma unroll
            for (int q = 0; q < 4; ++q) { e[q] = __expf(e[q] - gm); gs += e[q]; }
            const float gi = __fdividef(1.f, gs);
#pragma unroll
            for (int q = 0; q < 4; ++q) mu[fb + (size_t)q * Ll] = e[q] * gi;
        } else if (g == 1) {
#pragma unroll
            for (int q = 0; q < 4; ++q) {
                float sv, cv;
                __sincosf(2.f * (o[q] + geom_b[q]), &sv, &cv);
                cs2[fb + (size_t)q * Ll] = cv;
                sn2[fb + (size_t)q * Ll] = sv;
            }
        } else if (g == 2) {
#pragma unroll
            for (int q = 0; q < 4; ++q)
                bse[fb + (size_t)q * Ll] = softplusf(o[q] + geom_b[4 + q]) + 1e-4f;
        } else {
#pragma unroll
            for (int q = 0; q < 4; ++q)
                hyp[fb + (size_t)q * Ll] = softplusf(o[q] + geom_b[8 + q]);
        }
    }

    const int px16 = lane & 15;
    const int g2   = lane >> 4;
    {
        const int row = ch * 16 + px16;
        const short8 bh0 = *(const short8*)&xb16[row][g2 * 8];
        const short8 bh1 = *(const short8*)&xb16[row][32 + g2 * 8];

        f32x4 d0, d1, d2, d3;
#define PROJ_TILE(dst, t)                                              \
        {                                                              \
            f32x4 a_ = {0.f, 0.f, 0.f, 0.f};                           \
            a_ = __builtin_amdgcn_mfma_f32_16x16x32_bf16(af[2*(t)],   bh0, a_, 0, 0, 0); \
            a_ = __builtin_amdgcn_mfma_f32_16x16x32_bf16(af[2*(t)+1], bh1, a_, 0, 0, 0); \
            dst = a_;                                                  \
        }
        PROJ_TILE(d0, 0) PROJ_TILE(d1, 1) PROJ_TILE(d2, 2) PROJ_TILE(d3, 3)
#undef PROJ_TILE

        const int l = l0 + ch * 16 + px16;
        float* vrow = v + ((size_t)b * Ll + l) * 64 + g2 * 4;
        *(f32x4*)(vrow)      = d0;
        *(f32x4*)(vrow + 16) = d1;
        *(f32x4*)(vrow + 32) = d2;
        *(f32x4*)(vrow + 48) = d3;
    }
}

// ---------------- k23: fused compat + aggregation + MFMA pointwise ----------------
// TP=32, LDS 19968 B -> 8 blocks/CU (32 waves/CU, 2x R12's cap). Grid 4096;
// XCD-bijective swizzle gives each XCD exactly one batch image (512 tiles).
// Stage A: threads 0..127 = (px 0..31, r 0..3); waves 2-3 idle (other blocks
// fill the SIMD at 8-block residency). Stage B: wave w owns px w*8..+7,
// vv[3][10] hoisted; R12-style unpack+fma (no dot2: keeps VGPR<=64).
// Stage C: wave w -> o-tile w*16, 2 p-tiles, bias C-init.
__global__ __launch_bounds__(256, 8) void k23_fused(
    const float* __restrict__ mu,
    const float* __restrict__ cs2, const float* __restrict__ sn2,
    const float* __restrict__ bse, const float* __restrict__ hyp,
    const float* __restrict__ v,             // [B][L][64]
    const unsigned short* __restrict__ pwb16,// [64][256] bf16, m'-order
    const float* __restrict__ pw_b,          // [64]
    float* __restrict__ out)                 // [B][64][L]
{
    __shared__ unsigned wqpk[4][TP][6];      // 3,072 B
    __shared__ unsigned short agg[TP][264];  // 16,896 B

    const int tid = threadIdx.x;
    const int cpx = (int)(gridDim.x >> 3);   // 512
    const int bid = (int)((blockIdx.x & 7) * cpx + (blockIdx.x >> 3));
    const int pix0 = bid * TP;
    const int b = pix0 >> 14;
    const int l0 = pix0 & (Ll - 1);

    // ---- stage A: threads 0..127, (px, r) ----
    if (tid < 128) {
        const int px = tid & 31;
        const int r  = (tid >> 5) & 3;
        const int l  = l0 + px;
        const int hr = l >> 7;
        const int wc = l & (Ww - 1);
        const size_t fb = ((size_t)b * 4 + r) * Ll;

        const float cc = cs2[fb + l], sc = sn2[fb + l];
        const float bc = bse[fb + l], yc = hyp[fb + l];
        const float mc = mu[fb + l];

        float cmp[9];
        float sum = 0.f;
#pragma unroll
        for (int s = 0; s < 9; ++s) {
            const int dy = s / 3 - 1, dx = s % 3 - 1;
            float cv;
            if (dx == 0 && dy == 0) {
                cv = mc;
            } else {
                const int hh = hr + dy, ww = wc + dx;
                const int hcl = min(max(hh, 0), Hh - 1);
                const int wcl = min(max(ww, 0), Ww - 1);
                const bool inb = ((unsigned)hh < (unsigned)Hh) &
                                 ((unsigned)ww < (unsigned)Ww);
                const size_t ni = fb + hcl * Ww + wcl;
                const float cn = cs2[ni], sn = sn2[ni];
                const float bn = bse[ni], yn = hyp[ni];
                const float mun = inb ? mu[ni] : 0.f;
                const float c2 = cc + cn, s2 = sc + sn;
                const float h = sqrtf(fmaxf(c2 * c2 + s2 * s2, 1e-24f));
                const float rh = __fdividef(0.5f, h);
                float pu2, ps2;
                if (dx != 0 && dy != 0) {              // diagonal
                    const float t = 2.f * (float)(dx * dy) * (s2 * rh);
                    pu2 = 1.f + t; ps2 = 1.f - t;
                } else if (dx != 0) {                  // horizontal
                    pu2 = 0.5f + c2 * rh; ps2 = 0.5f - c2 * rh;
                } else {                               // vertical
                    pu2 = 0.5f - c2 * rh; ps2 = 0.5f + c2 * rh;
                }
                const float bp = 0.5f * (bc + bn);
                const float hp = 0.5f * (yc + yn);
                const float E = __expf(hp);
                const float iu = __fdividef(1.f, bp * E);   // 1/sigma_u
                const float is = E * E * iu;                // 1/sigma_s
                const float q = pu2 * (iu * iu) + ps2 * (is * is);
                cv = __expf(-q) * mun;
            }
            cmp[s] = cv;
            sum += cv;
        }
        const float inv = __fdividef(1.f, sum + 1e-6f);
        unsigned* wrow = &wqpk[r][px][0];
        wrow[0] = cvt_pk_bf16(cmp[0] * inv, cmp[1] * inv);  // s0,s1
        wrow[1] = cvt_pk_bf16(cmp[3] * inv, cmp[4] * inv);  // s3,s4
        wrow[2] = cvt_pk_bf16(cmp[6] * inv, cmp[7] * inv);  // s6,s7
        wrow[3] = cvt_pk_bf16(cmp[2] * inv, cmp[5] * inv);  // s2,s5
        wrow[4] = cvt_pk_bf16(cmp[8] * inv, 0.f);           // s8
    }
    __syncthreads();

    // ---- stage B: lane = channel, wave w owns px w*8..w*8+7 ----
    const int w = tid >> 6, c = tid & 63;
    {
        const int hr0  = l0 >> 7;
        const int rows[3] = { max(hr0 - 1, 0) * Ww, hr0 * Ww, min(hr0 + 1, Hh - 1) * Ww };
        const int colbase = (l0 & (Ww - 1)) + w * 8;
        const float* vb = v + ((size_t)b * Ll) * 64 + c;

        float vv[3][10];
#pragma unroll
        for (int ry = 0; ry < 3; ++ry)
#pragma unroll
            for (int cx = 0; cx < 10; ++cx) {
                const int col = min(max(colbase + cx - 1, 0), Ww - 1);
                vv[ry][cx] = vb[(size_t)(rows[ry] + col) * 64];
            }

#pragma unroll
        for (int p = 0; p < 8; ++p) {
            float av[4];
#pragma unroll
            for (int r = 0; r < 4; ++r) {
                const unsigned* wrow = &wqpk[r][w * 8 + p][0];
                const unsigned u0 = wrow[0], u1 = wrow[1], u2 = wrow[2],
                               u3 = wrow[3], u4 = wrow[4];
                float a;
                a = bflo(u0) * vv[0][p];                 // s0
                a = fmaf(bfhi(u0), vv[0][p + 1], a);     // s1
                a = fmaf(bflo(u3), vv[0][p + 2], a);     // s2
                a = fmaf(bflo(u1), vv[1][p],     a);     // s3
                a = fmaf(bfhi(u1), vv[1][p + 1], a);     // s4
                a = fmaf(bfhi(u3), vv[1][p + 2], a);     // s5
                a = fmaf(bflo(u2), vv[2][p],     a);     // s6
                a = fmaf(bfhi(u2), vv[2][p + 1], a);     // s7
                a = fmaf(bflo(u4), vv[2][p + 2], a);     // s8
                av[r] = a;
            }
            uint2 u;
            u.x = cvt_pk_bf16(av[0], av[1]);
            u.y = cvt_pk_bf16(av[2], av[3]);
            *((uint2*)(&agg[w * 8 + p][0]) + c) = u;    // m' = c*4+r
        }
    }

    // A fragments: issue before the barrier (in flight across it)
    const int ar    = tid & 15;
    const int chunk = (tid >> 4) & 3;
    const int o0    = w * 16;
    const unsigned short* aPtr = pwb16 + (o0 + ar) * 256 + chunk * 8;
    short8 af[8];
#pragma unroll
    for (int kt = 0; kt < 8; ++kt) af[kt] = *(const short8*)(aPtr + kt * 32);

    __syncthreads();

    // ---- stage C: MFMA pointwise, 2 p-tiles, A reused ----
    f32x4 d0, d1;
#pragma unroll
    for (int q = 0; q < 4; ++q) {
        const float bv = pw_b[o0 + chunk * 4 + q];
        d0[q] = bv; d1[q] = bv;
    }
    const unsigned short* b0 = &agg[ 0 + ar][chunk * 8];
    const unsigned short* b1 = &agg[16 + ar][chunk * 8];
#pragma unroll
    for (int kt = 0; kt < 8; ++kt) {
        d0 = __builtin_amdgcn_mfma_f32_16x16x32_bf16(af[kt], *(const short8*)(b0 + kt * 32), d0, 0, 0, 0);
        d1 = __builtin_amdgcn_mfma_f32_16x16x32_bf16(af[kt], *(const short8*)(b1 + kt * 32), d1, 0, 0, 0);
    }

#pragma unroll
    for (int q = 0; q < 4; ++q) {
        const int o = o0 + chunk * 4 + q;
        float* ob = out + ((size_t)b * Co + o) * Ll + l0 + ar;
        ob[0]  = d0[q];
        ob[16] = d1[q];
    }
}

// ---------------- launch ----------------
extern "C" void kernel_launch(void* const* d_in, const int* in_sizes, int n_in,
                              void* d_out, int out_size, void* d_ws, size_t ws_size,
                              hipStream_t stream)
{
    const float* x       = (const float*)d_in[0];
    const float* gate_w  = (const float*)d_in[1];
    const float* gate_b  = (const float*)d_in[2];
    const float* value_w = (const float*)d_in[3];
    const float* geom_w  = (const float*)d_in[4];
    const float* geom_b  = (const float*)d_in[5];
    const float* pw_w    = (const float*)d_in[6];
    const float* pw_b    = (const float*)d_in[7];
    float* out = (float*)d_out;

    float* ws  = (float*)d_ws;
    float* v    = ws;                                  // B*L*64   = 8388608
    float* mu   = v    + (size_t)Bx * Ll * 64;         // B*4*L    = 524288
    float* cs2  = mu   + (size_t)Bx * 4 * Ll;
    float* sn2  = cs2  + (size_t)Bx * 4 * Ll;
    float* bse  = sn2  + (size_t)Bx * 4 * Ll;
    float* hyp  = bse  + (size_t)Bx * 4 * Ll;
    float* wt16 = hyp  + (size_t)Bx * 4 * Ll;                 // 1024 f
    unsigned short* vwb16 = (unsigned short*)(wt16 + 1024);   // 4096 us
    unsigned short* pwb16 = vwb16 + 4096;                     // 16384 us
    // total ws: ~44 MB

    k0_pack_weights<<<8, 256, 0, stream>>>(gate_w, geom_w, value_w, pw_w,
                                           wt16, vwb16, pwb16);
    k1_project<<<NPIX / 64, 256, 0, stream>>>(x, vwb16, wt16, gate_b, geom_b,
                                              v, mu, cs2, sn2, bse, hyp);
    k23_fused<<<NPIX / TP, 256, 0, stream>>>(mu, cs2, sn2, bse, hyp,
                                             v, pwb16, pw_b, out);
}

// Round 16
// 70.375 us; speedup vs baseline: 1.3322x; 1.0000x over previous
//
#include <hip/hip_runtime.h>

namespace {
constexpr int Bx = 8, Cc = 64, Hh = 128, Ww = 128, Co = 64;
constexpr int Ll = Hh * Ww;        // 16384 = 2^14
constexpr int NPIX = Bx * Ll;      // 131072
constexpr int TP = 32;             // pixels per block in k23
}

using short8 = __attribute__((ext_vector_type(8))) short;
using f32x4  = __attribute__((ext_vector_type(4))) float;

__device__ __forceinline__ unsigned short f32_to_bf16(float f) {
    union { float f; unsigned u; } un; un.f = f;
    unsigned r = un.u + 0x7FFFu + ((un.u >> 16) & 1u);   // round-to-nearest-even
    return (unsigned short)(r >> 16);
}
// packed pair via HW converter (RNE); no builtin on gfx950 -> inline asm
__device__ __forceinline__ unsigned cvt_pk_bf16(float lo, float hi) {
    unsigned u;
    asm("v_cvt_pk_bf16_f32 %0, %1, %2" : "=v"(u) : "v"(lo), "v"(hi));
    return u;
}
__device__ __forceinline__ float bflo(unsigned u) {
    union { unsigned x; float f; } c; c.x = u << 16; return c.f;
}
__device__ __forceinline__ float bfhi(unsigned u) {
    union { unsigned x; float f; } c; c.x = u & 0xFFFF0000u; return c.f;
}

// ---------------- k0: pack weights (8 blocks) ----------------
__global__ __launch_bounds__(256) void k0_pack_weights(
    const float* __restrict__ gate_w,   // [4][64]
    const float* __restrict__ geom_w,   // [12][64]
    const float* __restrict__ value_w,  // [64][64]
    const float* __restrict__ pw_w,     // [64][256], m = r*64+c
    float* __restrict__ wt16,           // [64][16]
    unsigned short* __restrict__ vwb16, // [4096]
    unsigned short* __restrict__ pwb16) // [64][256] bf16, m' = c*4+r
{
    const int tid0 = blockIdx.x * 256 + threadIdx.x;
    for (int idx = tid0; idx < Cc * 16; idx += 2048) {
        const int c = idx >> 4, j = idx & 15;
        wt16[idx] = (j < 4) ? gate_w[j * Cc + c] : geom_w[(j - 4) * Cc + c];
    }
    for (int flat = tid0; flat < 4096; flat += 2048) {
        const int t    = flat >> 10;
        const int ks   = (flat >> 9) & 1;
        const int lane = (flat >> 3) & 63;
        const int jj   = flat & 7;
        const int j = t * 16 + (lane & 15);
        const int c = ks * 32 + ((lane >> 4) & 3) * 8 + jj;
        vwb16[flat] = f32_to_bf16(value_w[j * Cc + c]);
    }
    for (int idx = tid0; idx < Co * 256; idx += 2048) {
        const int o = idx >> 8, m = idx & 255;
        const int r = m >> 6, c = m & 63;
        pwb16[o * 256 + c * 4 + r] = f32_to_bf16(pw_w[idx]);
    }
}

__device__ __forceinline__ float softplusf(float v) {
    return v > 20.f ? v : log1pf(__expf(v));
}

// ---------------- k1: hybrid projections, 64 px/block (grid 2048) ----------------
// (unchanged from R12/R14: planar field outputs, fp32 pixel-major v)
__global__ __launch_bounds__(256) void k1_project(
    const float* __restrict__ x,       // [B][64][L]
    const unsigned short* __restrict__ vwb16,
    const float* __restrict__ wt16,    // [64][16]
    const float* __restrict__ gate_b,  // [4]
    const float* __restrict__ geom_b,  // [12]
    float* __restrict__ v,             // [B][L][64]  (pixel-major)
    float* __restrict__ mu,            // [B][4][L]
    float* __restrict__ cs2, float* __restrict__ sn2,
    float* __restrict__ bse, float* __restrict__ hyp)  // each [B][4][L]
{
    __shared__ unsigned short xb16[64][72];   // 9,216 B
    __shared__ float part[4][64][17];         // 17,408 B; total 26.6 KB

    const int tid  = threadIdx.x;
    const int px   = tid & 63;
    const int ch   = tid >> 6;               // channel-quarter / wave id
    const int lane = tid & 63;
    const int pix0 = blockIdx.x * 64;
    const int b    = pix0 >> 14;
    const int l0   = pix0 & (Ll - 1);

    float acc[16];
#pragma unroll
    for (int j = 0; j < 16; ++j) acc[j] = 0.f;

    const float* xb = x + (size_t)b * Cc * Ll + (l0 + px);
#pragma unroll
    for (int j0 = 0; j0 < 16; j0 += 8) {
        float xv[8];
#pragma unroll
        for (int j = 0; j < 8; ++j) xv[j] = xb[(size_t)(ch * 16 + j0 + j) * Ll];
        uint4 ph;
        unsigned* hp = (unsigned*)&ph;
#pragma unroll
        for (int j = 0; j < 4; ++j)
            hp[j] = cvt_pk_bf16(xv[2 * j], xv[2 * j + 1]);
        *(uint4*)&xb16[px][ch * 16 + j0] = ph;
#pragma unroll
        for (int j = 0; j < 8; ++j) {
            const float* wr = wt16 + (ch * 16 + j0 + j) * 16;   // uniform
#pragma unroll
            for (int jj = 0; jj < 16; ++jj) acc[jj] = fmaf(wr[jj], xv[j], acc[jj]);
        }
    }
#pragma unroll
    for (int jj = 0; jj < 16; ++jj) part[ch][px][jj] = acc[jj];

    short8 af[8];
#pragma unroll
    for (int i = 0; i < 8; ++i)
        af[i] = *(const short8*)(vwb16 + ((size_t)(i * 64 + lane)) * 8);

    __syncthreads();

    {
        const int g = ch;
        const int l = l0 + px;
        const size_t fb = (size_t)b * 4 * Ll + l;
        float o[4];
#pragma unroll
        for (int q = 0; q < 4; ++q)
            o[q] = part[0][px][4 * g + q] + part[1][px][4 * g + q]
                 + part[2][px][4 * g + q] + part[3][px][4 * g + q];
        if (g == 0) {
            float e[4], gm = -1e30f;
#pragma unroll
            for (int q = 0; q < 4; ++q) { e[q] = o[q] + gate_b[q]; gm = fmaxf(gm, e[q]); }
            float gs = 0.f;
#pragma unroll
            for (int q = 0; q < 4; ++q) { e[q] = __expf(e[q] - gm); gs += e[q]; }
            const float gi = __fdividef(1.f, gs);
#pragma unroll
            for (int q = 0; q < 4; ++q) mu[fb + (size_t)q * Ll] = e[q] * gi;
        } else if (g == 1) {
#pragma unroll
            for (int q = 0; q < 4; ++q) {
                float sv, cv;
                __sincosf(2.f * (o[q] + geom_b[q]), &sv, &cv);
                cs2[fb + (size_t)q * Ll] = cv;
                sn2[fb + (size_t)q * Ll] = sv;
            }
        } else if (g == 2) {
#pragma unroll
            for (int q = 0; q < 4; ++q)
                bse[fb + (size_t)q * Ll] = softplusf(o[q] + geom_b[4 + q]) + 1e-4f;
        } else {
#pragma unroll
            for (int q = 0; q < 4; ++q)
                hyp[fb + (size_t)q * Ll] = softplusf(o[q] + geom_b[8 + q]);
        }
    }

    const int px16 = lane & 15;
    const int g2   = lane >> 4;
    {
        const int row = ch * 16 + px16;
        const short8 bh0 = *(const short8*)&xb16[row][g2 * 8];
        const short8 bh1 = *(const short8*)&xb16[row][32 + g2 * 8];

        f32x4 d0, d1, d2, d3;
#define PROJ_TILE(dst, t)                                              \
        {                                                              \
            f32x4 a_ = {0.f, 0.f, 0.f, 0.f};                           \
            a_ = __builtin_amdgcn_mfma_f32_16x16x32_bf16(af[2*(t)],   bh0, a_, 0, 0, 0); \
            a_ = __builtin_amdgcn_mfma_f32_16x16x32_bf16(af[2*(t)+1], bh1, a_, 0, 0, 0); \
            dst = a_;                                                  \
        }
        PROJ_TILE(d0, 0) PROJ_TILE(d1, 1) PROJ_TILE(d2, 2) PROJ_TILE(d3, 3)
#undef PROJ_TILE

        const int l = l0 + ch * 16 + px16;
        float* vrow = v + ((size_t)b * Ll + l) * 64 + g2 * 4;
        *(f32x4*)(vrow)      = d0;
        *(f32x4*)(vrow + 16) = d1;
        *(f32x4*)(vrow + 32) = d2;
        *(f32x4*)(vrow + 48) = d3;
    }
}

// ---------------- k23: fused compat + aggregation + MFMA pointwise ----------------
// TP=32, LDS 19968 B -> 8 blocks/CU (32 waves/CU, 2x R12's cap). Grid 4096;
// XCD-bijective swizzle gives each XCD exactly one batch image (512 tiles).
// Stage A: threads 0..127 = (px 0..31, r 0..3); waves 2-3 idle (other blocks
// fill the SIMD at 8-block residency). Stage B: wave w owns px w*8..+7,
// vv[3][10] hoisted; R12-style unpack+fma (no dot2: keeps VGPR<=64).
// Stage C: wave w -> o-tile w*16, 2 p-tiles, bias C-init.
__global__ __launch_bounds__(256, 8) void k23_fused(
    const float* __restrict__ mu,
    const float* __restrict__ cs2, const float* __restrict__ sn2,
    const float* __restrict__ bse, const float* __restrict__ hyp,
    const float* __restrict__ v,             // [B][L][64]
    const unsigned short* __restrict__ pwb16,// [64][256] bf16, m'-order
    const float* __restrict__ pw_b,          // [64]
    float* __restrict__ out)                 // [B][64][L]
{
    __shared__ unsigned wqpk[4][TP][6];      // 3,072 B
    __shared__ unsigned short agg[TP][264];  // 16,896 B

    const int tid = threadIdx.x;
    const int cpx = (int)(gridDim.x >> 3);   // 512
    const int bid = (int)((blockIdx.x & 7) * cpx + (blockIdx.x >> 3));
    const int pix0 = bid * TP;
    const int b = pix0 >> 14;
    const int l0 = pix0 & (Ll - 1);

    // ---- stage A: threads 0..127, (px, r) ----
    if (tid < 128) {
        const int px = tid & 31;
        const int r  = (tid >> 5) & 3;
        const int l  = l0 + px;
        const int hr = l >> 7;
        const int wc = l & (Ww - 1);
        const size_t fb = ((size_t)b * 4 + r) * Ll;

        const float cc = cs2[fb + l], sc = sn2[fb + l];
        const float bc = bse[fb + l], yc = hyp[fb + l];
        const float mc = mu[fb + l];

        float cmp[9];
        float sum = 0.f;
#pragma unroll
        for (int s = 0; s < 9; ++s) {
            const int dy = s / 3 - 1, dx = s % 3 - 1;
            float cv;
            if (dx == 0 && dy == 0) {
                cv = mc;
            } else {
                const int hh = hr + dy, ww = wc + dx;
                const int hcl = min(max(hh, 0), Hh - 1);
                const int wcl = min(max(ww, 0), Ww - 1);
                const bool inb = ((unsigned)hh < (unsigned)Hh) &
                                 ((unsigned)ww < (unsigned)Ww);
                const size_t ni = fb + hcl * Ww + wcl;
                const float cn = cs2[ni], sn = sn2[ni];
                const float bn = bse[ni], yn = hyp[ni];
                const float mun = inb ? mu[ni] : 0.f;
                const float c2 = cc + cn, s2 = sc + sn;
                const float h = sqrtf(fmaxf(c2 * c2 + s2 * s2, 1e-24f));
                const float rh = __fdividef(0.5f, h);
                float pu2, ps2;
                if (dx != 0 && dy != 0) {              // diagonal
                    const float t = 2.f * (float)(dx * dy) * (s2 * rh);
                    pu2 = 1.f + t; ps2 = 1.f - t;
                } else if (dx != 0) {                  // horizontal
                    pu2 = 0.5f + c2 * rh; ps2 = 0.5f - c2 * rh;
                } else {                               // vertical
                    pu2 = 0.5f - c2 * rh; ps2 = 0.5f + c2 * rh;
                }
                const float bp = 0.5f * (bc + bn);
                const float hp = 0.5f * (yc + yn);
                const float E = __expf(hp);
                const float iu = __fdividef(1.f, bp * E);   // 1/sigma_u
                const float is = E * E * iu;                // 1/sigma_s
                const float q = pu2 * (iu * iu) + ps2 * (is * is);
                cv = __expf(-q) * mun;
            }
            cmp[s] = cv;
            sum += cv;
        }
        const float inv = __fdividef(1.f, sum + 1e-6f);
        unsigned* wrow = &wqpk[r][px][0];
        wrow[0] = cvt_pk_bf16(cmp[0] * inv, cmp[1] * inv);  // s0,s1
        wrow[1] = cvt_pk_bf16(cmp[3] * inv, cmp[4] * inv);  // s3,s4
        wrow[2] = cvt_pk_bf16(cmp[6] * inv, cmp[7] * inv);  // s6,s7
        wrow[3] = cvt_pk_bf16(cmp[2] * inv, cmp[5] * inv);  // s2,s5
        wrow[4] = cvt_pk_bf16(cmp[8] * inv, 0.f);           // s8
    }
    __syncthreads();

    // ---- stage B: lane = channel, wave w owns px w*8..w*8+7 ----
    const int w = tid >> 6, c = tid & 63;
    {
        const int hr0  = l0 >> 7;
        const int rows[3] = { max(hr0 - 1, 0) * Ww, hr0 * Ww, min(hr0 + 1, Hh - 1) * Ww };
        const int colbase = (l0 & (Ww - 1)) + w * 8;
        const float* vb = v + ((size_t)b * Ll) * 64 + c;

        float vv[3][10];
#pragma unroll
        for (int ry = 0; ry < 3; ++ry)
#pragma unroll
            for (int cx = 0; cx < 10; ++cx) {
                const int col = min(max(colbase + cx - 1, 0), Ww - 1);
                vv[ry][cx] = vb[(size_t)(rows[ry] + col) * 64];
            }

#pragma unroll
        for (int p = 0; p < 8; ++p) {
            float av[4];
#pragma unroll
            for (int r = 0; r < 4; ++r) {
                const unsigned* wrow = &wqpk[r][w * 8 + p][0];
                const unsigned u0 = wrow[0], u1 = wrow[1], u2 = wrow[2],
                               u3 = wrow[3], u4 = wrow[4];
                float a;
                a = bflo(u0) * vv[0][p];                 // s0
                a = fmaf(bfhi(u0), vv[0][p + 1], a);     // s1
                a = fmaf(bflo(u3), vv[0][p + 2], a);     // s2
                a = fmaf(bflo(u1), vv[1][p],     a);     // s3
                a = fmaf(bfhi(u1), vv[1][p + 1], a);     // s4
                a = fmaf(bfhi(u3), vv[1][p + 2], a);     // s5
                a = fmaf(bflo(u2), vv[2][p],     a);     // s6
                a = fmaf(bfhi(u2), vv[2][p + 1], a);     // s7
                a = fmaf(bflo(u4), vv[2][p + 2], a);     // s8
                av[r] = a;
            }
            uint2 u;
            u.x = cvt_pk_bf16(av[0], av[1]);
            u.y = cvt_pk_bf16(av[2], av[3]);
            *((uint2*)(&agg[w * 8 + p][0]) + c) = u;    // m' = c*4+r
        }
    }

    // A fragments: issue before the barrier (in flight across it)
    const int ar    = tid & 15;
    const int chunk = (tid >> 4) & 3;
    const int o0    = w * 16;
    const unsigned short* aPtr = pwb16 + (o0 + ar) * 256 + chunk * 8;
    short8 af[8];
#pragma unroll
    for (int kt = 0; kt < 8; ++kt) af[kt] = *(const short8*)(aPtr + kt * 32);

    __syncthreads();

    // ---- stage C: MFMA pointwise, 2 p-tiles, A reused ----
    f32x4 d0, d1;
#pragma unroll
    for (int q = 0; q < 4; ++q) {
        const float bv = pw_b[o0 + chunk * 4 + q];
        d0[q] = bv; d1[q] = bv;
    }
    const unsigned short* b0 = &agg[ 0 + ar][chunk * 8];
    const unsigned short* b1 = &agg[16 + ar][chunk * 8];
#pragma unroll
    for (int kt = 0; kt < 8; ++kt) {
        d0 = __builtin_amdgcn_mfma_f32_16x16x32_bf16(af[kt], *(const short8*)(b0 + kt * 32), d0, 0, 0, 0);
        d1 = __builtin_amdgcn_mfma_f32_16x16x32_bf16(af[kt], *(const short8*)(b1 + kt * 32), d1, 0, 0, 0);
    }

#pragma unroll
    for (int q = 0; q < 4; ++q) {
        const int o = o0 + chunk * 4 + q;
        float* ob = out + ((size_t)b * Co + o) * Ll + l0 + ar;
        ob[0]  = d0[q];
        ob[16] = d1[q];
    }
}

// ---------------- launch ----------------
extern "C" void kernel_launch(void* const* d_in, const int* in_sizes, int n_in,
                              void* d_out, int out_size, void* d_ws, size_t ws_size,
                              hipStream_t stream)
{
    const float* x       = (const float*)d_in[0];
    const float* gate_w  = (const float*)d_in[1];
    const float* gate_b  = (const float*)d_in[2];
    const float* value_w = (const float*)d_in[3];
    const float* geom_w  = (const float*)d_in[4];
    const float* geom_b  = (const float*)d_in[5];
    const float* pw_w    = (const float*)d_in[6];
    const float* pw_b    = (const float*)d_in[7];
    float* out = (float*)d_out;

    float* ws  = (float*)d_ws;
    float* v    = ws;                                  // B*L*64   = 8388608
    float* mu   = v    + (size_t)Bx * Ll * 64;         // B*4*L    = 524288
    float* cs2  = mu   + (size_t)Bx * 4 * Ll;
    float* sn2  = cs2  + (size_t)Bx * 4 * Ll;
    float* bse  = sn2  + (size_t)Bx * 4 * Ll;
    float* hyp  = bse  + (size_t)Bx * 4 * Ll;
    float* wt16 = hyp  + (size_t)Bx * 4 * Ll;                 // 1024 f
    unsigned short* vwb16 = (unsigned short*)(wt16 + 1024);   // 4096 us
    unsigned short* pwb16 = vwb16 + 4096;                     // 16384 us
    // total ws: ~44 MB

    k0_pack_weights<<<8, 256, 0, stream>>>(gate_w, geom_w, value_w, pw_w,
                                           wt16, vwb16, pwb16);
    k1_project<<<NPIX / 64, 256, 0, stream>>>(x, vwb16, wt16, gate_b, geom_b,
                                              v, mu, cs2, sn2, bse, hyp);
    k23_fused<<<NPIX / TP, 256, 0, stream>>>(mu, cs2, sn2, bse, hyp,
                                             v, pwb16, pw_b, out);
}